// Round 3
// baseline (580.194 us; speedup 1.0000x reference)
//
#include <hip/hip_runtime.h>
#include <math.h>

#define D_MODEL 1024
#define NHEAD   16
#define DK      64
#define BATCH   4
#define SEQ     2048
#define MROWS   8192

typedef __attribute__((ext_vector_type(4)))  float f32x4;
typedef __attribute__((ext_vector_type(16))) float f32x16;
typedef __attribute__((ext_vector_type(8)))  short bf16x8;

// fold 1/sqrt(dk) * log2(e) into stored Q -> softmax runs in exp2 domain
#define QSCALE 0.18033688011112042f

__device__ __forceinline__ unsigned int cvt_pk_bf16(float lo, float hi) {
  unsigned int r;
  asm("v_cvt_pk_bf16_f32 %0, %1, %2" : "=v"(r) : "v"(lo), "v"(hi));
  return r;
}

// ---------------- fused fp32 -> bf16 convert, 7 segments ----------------
// grid = 3*4096 (activations, 8.39M elems each) + 4*512 (weights, 1.05M each)
__global__ __launch_bounds__(256) void cvt_all(
    const float* __restrict__ q, const float* __restrict__ k, const float* __restrict__ v,
    const float* __restrict__ wq, const float* __restrict__ wk,
    const float* __restrict__ wv, const float* __restrict__ wo,
    unsigned short* __restrict__ qb, unsigned short* __restrict__ kb,
    unsigned short* __restrict__ vb, unsigned short* __restrict__ wqb,
    unsigned short* __restrict__ wkb, unsigned short* __restrict__ wvb,
    unsigned short* __restrict__ wob) {
  const int bid = blockIdx.x;
  const float* src; unsigned short* dst; int off;
  if      (bid < 4096)  { src = q;  dst = qb;  off = bid; }
  else if (bid < 8192)  { src = k;  dst = kb;  off = bid - 4096; }
  else if (bid < 12288) { src = v;  dst = vb;  off = bid - 8192; }
  else if (bid < 12800) { src = wq; dst = wqb; off = bid - 12288; }
  else if (bid < 13312) { src = wk; dst = wkb; off = bid - 12800; }
  else if (bid < 13824) { src = wv; dst = wvb; off = bid - 13312; }
  else                  { src = wo; dst = wob; off = bid - 13824; }
  const size_t i = (size_t)off * 256 + threadIdx.x;  // 8-elem chunk index
  const float4* p = (const float4*)src + i * 2;
  const float4 a = p[0], b = p[1];
  int4 o;
  o.x = (int)cvt_pk_bf16(a.x, a.y);
  o.y = (int)cvt_pk_bf16(a.z, a.w);
  o.z = (int)cvt_pk_bf16(b.x, b.y);
  o.w = (int)cvt_pk_bf16(b.z, b.w);
  *(int4*)(dst + i * 8) = o;
}

// ---------------- fused QKV projection GEMM ----------------
// grid (24, 64): blockIdx.x>>3 = sector (0=Q,1=K,2=V). 128x128 tile, BK=32,
// 4 waves x 64x64 quadrant, 16x16x32 bf16 MFMA, global_load_lds staging.
// Q/K out: plain bf16 [B*S][1024] (Q pre-scaled). V out: [B,H,64,S] transposed.
__global__ __launch_bounds__(256) void gemm_qkv(
    const unsigned short* __restrict__ Aq, const unsigned short* __restrict__ Ak,
    const unsigned short* __restrict__ Av,
    const unsigned short* __restrict__ Wq, const unsigned short* __restrict__ Wk,
    const unsigned short* __restrict__ Wv,
    const float* __restrict__ bq, const float* __restrict__ bk,
    const float* __restrict__ bv,
    unsigned short* __restrict__ Qo, unsigned short* __restrict__ Ko,
    unsigned short* __restrict__ Vo) {
  __shared__ unsigned short Asb[128 * 32];
  __shared__ unsigned short Bsb[128 * 32];
  const int t = threadIdx.x;
  const int lane = t & 63, w = t >> 6;
  const int wr = w >> 1, wc = w & 1;
  const int g = lane >> 4, cl = lane & 15;
  const int sector = blockIdx.x >> 3;
  const int n0 = (blockIdx.x & 7) * 128;
  const int m0 = blockIdx.y * 128;
  const unsigned short* A = sector == 0 ? Aq : sector == 1 ? Ak : Av;
  const unsigned short* W = sector == 0 ? Wq : sector == 1 ? Wk : Wv;
  const float* bias = sector == 0 ? bq : sector == 1 ? bk : bv;

  f32x4 acc[4][4];
#pragma unroll
  for (int i = 0; i < 4; ++i)
#pragma unroll
    for (int j = 0; j < 4; ++j) acc[i][j] = (f32x4){0.f, 0.f, 0.f, 0.f};

  for (int k0 = 0; k0 < D_MODEL; k0 += 32) {
    __syncthreads();
#pragma unroll
    for (int p = 0; p < 2; ++p) {
      const int c = p * 256 + t;
      const unsigned short* ga = A + (size_t)(m0 + (c >> 2)) * D_MODEL + k0 + (c & 3) * 8;
      const unsigned short* gw = W + (size_t)(n0 + (c >> 2)) * D_MODEL + k0 + (c & 3) * 8;
      __builtin_amdgcn_global_load_lds(
          (const __attribute__((address_space(1))) unsigned int*)ga,
          (__attribute__((address_space(3))) unsigned int*)(Asb + (size_t)c * 8), 16, 0, 0);
      __builtin_amdgcn_global_load_lds(
          (const __attribute__((address_space(1))) unsigned int*)gw,
          (__attribute__((address_space(3))) unsigned int*)(Bsb + (size_t)c * 8), 16, 0, 0);
    }
    __syncthreads();

    bf16x8 af[4], bfr[4];
#pragma unroll
    for (int mi = 0; mi < 4; ++mi)
      af[mi] = *(const bf16x8*)&Asb[(wr * 64 + mi * 16 + cl) * 32 + g * 8];
#pragma unroll
    for (int ni = 0; ni < 4; ++ni)
      bfr[ni] = *(const bf16x8*)&Bsb[(wc * 64 + ni * 16 + cl) * 32 + g * 8];
#pragma unroll
    for (int mi = 0; mi < 4; ++mi)
#pragma unroll
      for (int ni = 0; ni < 4; ++ni)
        acc[mi][ni] = __builtin_amdgcn_mfma_f32_16x16x32_bf16(af[mi], bfr[ni], acc[mi][ni], 0, 0, 0);
  }

  if (sector < 2) {
    unsigned short* O = sector == 0 ? Qo : Ko;
    const float sc = sector == 0 ? QSCALE : 1.0f;
#pragma unroll
    for (int mi = 0; mi < 4; ++mi)
#pragma unroll
      for (int ni = 0; ni < 4; ++ni) {
        const int nn = n0 + wc * 64 + ni * 16 + cl;
        const float bvv = bias[nn];
#pragma unroll
        for (int j = 0; j < 4; ++j) {
          const int mm = m0 + wr * 64 + mi * 16 + 4 * g + j;
          const float v = (acc[mi][ni][j] + bvv) * sc;
          O[(size_t)mm * D_MODEL + nn] = (unsigned short)cvt_pk_bf16(v, v);
        }
      }
  } else {
#pragma unroll
    for (int mi = 0; mi < 4; ++mi)
#pragma unroll
      for (int ni = 0; ni < 4; ++ni) {
        const int nn = n0 + wc * 64 + ni * 16 + cl;
        const int h = nn >> 6, d = nn & 63;
        const float bvv = bias[nn];
        const int mmb = m0 + wr * 64 + mi * 16 + 4 * g;   // j=0..3 -> consecutive s
        const int b = mmb >> 11, s = mmb & (SEQ - 1);
        uint2 w2;
        w2.x = cvt_pk_bf16(acc[mi][ni][0] + bvv, acc[mi][ni][1] + bvv);
        w2.y = cvt_pk_bf16(acc[mi][ni][2] + bvv, acc[mi][ni][3] + bvv);
        *(uint2*)&Vo[(((size_t)(b * NHEAD + h)) * DK + d) * SEQ + s] = w2;
      }
  }
}

// ---------------- output projection GEMM (bf16 in, fp32 out) ----------------
__global__ __launch_bounds__(256) void gemm_out(const unsigned short* __restrict__ A,
                                                const unsigned short* __restrict__ W,
                                                const float* __restrict__ bias,
                                                float* __restrict__ C) {
  __shared__ unsigned short Asb[128 * 32];
  __shared__ unsigned short Bsb[128 * 32];
  const int t = threadIdx.x;
  const int lane = t & 63, w = t >> 6;
  const int wr = w >> 1, wc = w & 1;
  const int g = lane >> 4, cl = lane & 15;
  const int m0 = blockIdx.y * 128, n0 = blockIdx.x * 128;

  f32x4 acc[4][4];
#pragma unroll
  for (int i = 0; i < 4; ++i)
#pragma unroll
    for (int j = 0; j < 4; ++j) acc[i][j] = (f32x4){0.f, 0.f, 0.f, 0.f};

  for (int k0 = 0; k0 < D_MODEL; k0 += 32) {
    __syncthreads();
#pragma unroll
    for (int p = 0; p < 2; ++p) {
      const int c = p * 256 + t;
      const unsigned short* ga = A + (size_t)(m0 + (c >> 2)) * D_MODEL + k0 + (c & 3) * 8;
      const unsigned short* gw = W + (size_t)(n0 + (c >> 2)) * D_MODEL + k0 + (c & 3) * 8;
      __builtin_amdgcn_global_load_lds(
          (const __attribute__((address_space(1))) unsigned int*)ga,
          (__attribute__((address_space(3))) unsigned int*)(Asb + (size_t)c * 8), 16, 0, 0);
      __builtin_amdgcn_global_load_lds(
          (const __attribute__((address_space(1))) unsigned int*)gw,
          (__attribute__((address_space(3))) unsigned int*)(Bsb + (size_t)c * 8), 16, 0, 0);
    }
    __syncthreads();

    bf16x8 af[4], bfr[4];
#pragma unroll
    for (int mi = 0; mi < 4; ++mi)
      af[mi] = *(const bf16x8*)&Asb[(wr * 64 + mi * 16 + cl) * 32 + g * 8];
#pragma unroll
    for (int ni = 0; ni < 4; ++ni)
      bfr[ni] = *(const bf16x8*)&Bsb[(wc * 64 + ni * 16 + cl) * 32 + g * 8];
#pragma unroll
    for (int mi = 0; mi < 4; ++mi)
#pragma unroll
      for (int ni = 0; ni < 4; ++ni)
        acc[mi][ni] = __builtin_amdgcn_mfma_f32_16x16x32_bf16(af[mi], bfr[ni], acc[mi][ni], 0, 0, 0);
  }

#pragma unroll
  for (int mi = 0; mi < 4; ++mi)
#pragma unroll
    for (int ni = 0; ni < 4; ++ni) {
      const int nn = n0 + wc * 64 + ni * 16 + cl;
      const float bvv = bias[nn];
#pragma unroll
      for (int j = 0; j < 4; ++j) {
        const int mm = m0 + wr * 64 + mi * 16 + 4 * g + j;
        C[(size_t)mm * D_MODEL + nn] = acc[mi][ni][j] + bvv;
      }
    }
}

// ---------------- Flash attention, swapped-QK^T 32x32 MFMA ----------------
// 4 independent waves/block, 32 q-rows/wave, KV tile 64, no LDS, no syncthreads.
// S^T = mfma(K, Q): lane l holds q = l&31, h = l>>5; per 32-key chunk lane has
// 16 scores at keys crow(r,h) = (r&3) + 8*(r>>2) + 4h; partner l^32 has the rest.
// Softmax per-lane scalar (m, lsum) + one xor-32 exchange. defer-max THR=8 (log2).
// P -> bf16 via v_cvt_pk_bf16_f32 + v_permlane32_swap -> PV B-frags directly.
// PV: O^T = mfma(V^T_frag, P_frag); V^T frags contiguous from Vt [B,H,64,S].
__global__ __launch_bounds__(256) void attn_mfma(const unsigned short* __restrict__ Qh,
                                                 const unsigned short* __restrict__ Kh,
                                                 const unsigned short* __restrict__ Vt,
                                                 unsigned short* __restrict__ Ctx) {
  const int t = threadIdx.x;
  const int lane = t & 63, w = t >> 6;
  const int q32 = lane & 31, h = lane >> 5;
  const int head = blockIdx.y, b = blockIdx.z;
  const int q0 = blockIdx.x * 128 + w * 32;

  const unsigned short* Qp = Qh + ((size_t)b * SEQ + q0) * D_MODEL + head * DK;
  const unsigned short* Kp = Kh + (size_t)b * SEQ * D_MODEL + head * DK;
  const unsigned short* Vp = Vt + ((size_t)(b * NHEAD + head)) * DK * SEQ;

  // Q B-frags (loaded once): qf[dc] = Q[q0+q32][dc*16 + h*8 + 0..7]
  bf16x8 qf[4];
#pragma unroll
  for (int dc = 0; dc < 4; ++dc)
    qf[dc] = *(const bf16x8*)&Qp[(size_t)q32 * D_MODEL + dc * 16 + h * 8];

  f32x16 oc[2];
#pragma unroll
  for (int d0 = 0; d0 < 2; ++d0)
#pragma unroll
    for (int r = 0; r < 16; ++r) oc[d0][r] = 0.f;
  float m = -1e30f, lsum = 0.f;

  for (int kt = 0; kt < SEQ / 64; ++kt) {
    const int key0 = kt * 64;

    // QK^T (swapped): st[kg] = S^T[32 keys][32 q] chunk
    f32x16 st[2];
#pragma unroll
    for (int kg = 0; kg < 2; ++kg) {
#pragma unroll
      for (int r = 0; r < 16; ++r) st[kg][r] = 0.f;
#pragma unroll
      for (int dc = 0; dc < 4; ++dc) {
        const bf16x8 kf = *(const bf16x8*)&Kp[(size_t)(key0 + kg * 32 + q32) * D_MODEL +
                                              dc * 16 + h * 8];
        st[kg] = __builtin_amdgcn_mfma_f32_32x32x16_bf16(kf, qf[dc], st[kg], 0, 0, 0);
      }
    }

    // tile max (in-lane tree + partner exchange)
    float tmx[16];
#pragma unroll
    for (int r = 0; r < 16; ++r) tmx[r] = fmaxf(st[0][r], st[1][r]);
#pragma unroll
    for (int s = 8; s > 0; s >>= 1)
#pragma unroll
      for (int r = 0; r < 8; ++r)
        if (r < s) tmx[r] = fmaxf(tmx[r], tmx[r + s]);
    float pmax = fmaxf(tmx[0], __shfl_xor(tmx[0], 32));

    // defer-max rescale (wave-uniform)
    if (!__all(pmax - m <= 8.0f)) {
      const float mnew = fmaxf(m, pmax);
      const float fsc = exp2f(m - mnew);
      m = mnew;
      lsum *= fsc;
#pragma unroll
      for (int d0 = 0; d0 < 2; ++d0)
#pragma unroll
        for (int r = 0; r < 16; ++r) oc[d0][r] *= fsc;
    }

    // p = exp2(s - m); accumulate row-sum (own half)
    float rs[4] = {0.f, 0.f, 0.f, 0.f};
#pragma unroll
    for (int kg = 0; kg < 2; ++kg)
#pragma unroll
      for (int r = 0; r < 16; ++r) {
        const float p = exp2f(st[kg][r] - m);
        st[kg][r] = p;
        rs[r & 3] += p;
      }
    lsum += (rs[0] + rs[1]) + (rs[2] + rs[3]);

    // P -> bf16 PV fragments: 16 cvt_pk + 8 permlane32_swap
    unsigned int paw[4][4];
#pragma unroll
    for (int kg = 0; kg < 2; ++kg) {
      {
        auto s0 = __builtin_amdgcn_permlane32_swap(
            cvt_pk_bf16(st[kg][0], st[kg][1]), cvt_pk_bf16(st[kg][4], st[kg][5]), false, false);
        auto s1 = __builtin_amdgcn_permlane32_swap(
            cvt_pk_bf16(st[kg][2], st[kg][3]), cvt_pk_bf16(st[kg][6], st[kg][7]), false, false);
        paw[kg * 2][0] = s0[0]; paw[kg * 2][2] = s0[1];
        paw[kg * 2][1] = s1[0]; paw[kg * 2][3] = s1[1];
      }
      {
        auto s0 = __builtin_amdgcn_permlane32_swap(
            cvt_pk_bf16(st[kg][8], st[kg][9]), cvt_pk_bf16(st[kg][12], st[kg][13]), false, false);
        auto s1 = __builtin_amdgcn_permlane32_swap(
            cvt_pk_bf16(st[kg][10], st[kg][11]), cvt_pk_bf16(st[kg][14], st[kg][15]), false, false);
        paw[kg * 2 + 1][0] = s0[0]; paw[kg * 2 + 1][2] = s0[1];
        paw[kg * 2 + 1][1] = s1[0]; paw[kg * 2 + 1][3] = s1[1];
      }
    }

    // PV: oc[d0] += V^T_frag x P_frag
#pragma unroll
    for (int ks = 0; ks < 4; ++ks) {
      union { unsigned int u[4]; bf16x8 v; } pu;
      pu.u[0] = paw[ks][0]; pu.u[1] = paw[ks][1];
      pu.u[2] = paw[ks][2]; pu.u[3] = paw[ks][3];
#pragma unroll
      for (int d0 = 0; d0 < 2; ++d0) {
        const bf16x8 vf = *(const bf16x8*)&Vp[(size_t)(d0 * 32 + q32) * SEQ + key0 +
                                              ks * 16 + h * 8];
        oc[d0] = __builtin_amdgcn_mfma_f32_32x32x16_bf16(vf, pu.v, oc[d0], 0, 0, 0);
      }
    }
  }

  // epilogue: combine partner sums, normalize, pack 4 bf16 (8B) stores
  lsum += __shfl_xor(lsum, 32);
  const float inv = 1.f / lsum;
  unsigned short* Cp = Ctx + ((size_t)b * SEQ + q0 + q32) * D_MODEL + head * DK;
#pragma unroll
  for (int d0 = 0; d0 < 2; ++d0)
#pragma unroll
    for (int rq = 0; rq < 4; ++rq) {
      const int dbase = d0 * 32 + 8 * rq + 4 * h;
      uint2 w2;
      w2.x = cvt_pk_bf16(oc[d0][4 * rq + 0] * inv, oc[d0][4 * rq + 1] * inv);
      w2.y = cvt_pk_bf16(oc[d0][4 * rq + 2] * inv, oc[d0][4 * rq + 3] * inv);
      *(uint2*)(Cp + dbase) = w2;
    }
}

extern "C" void kernel_launch(void* const* d_in, const int* in_sizes, int n_in,
                              void* d_out, int out_size, void* d_ws, size_t ws_size,
                              hipStream_t stream) {
  const float* query = (const float*)d_in[0];
  const float* key   = (const float*)d_in[1];
  const float* value = (const float*)d_in[2];
  const float* wq = (const float*)d_in[3];
  const float* bq = (const float*)d_in[4];
  const float* wk = (const float*)d_in[5];
  const float* bk = (const float*)d_in[6];
  const float* wv = (const float*)d_in[7];
  const float* bv = (const float*)d_in[8];
  const float* wo = (const float*)d_in[9];
  const float* bo = (const float*)d_in[10];

  unsigned short* ws = (unsigned short*)d_ws;
  const size_t TA = (size_t)MROWS * D_MODEL;
  const size_t TW = (size_t)D_MODEL * D_MODEL;
  unsigned short* qb  = ws;
  unsigned short* kb  = qb + TA;
  unsigned short* vb  = kb + TA;
  unsigned short* wqb = vb + TA;
  unsigned short* wkb = wqb + TW;
  unsigned short* wvb = wkb + TW;
  unsigned short* wob = wvb + TW;
  unsigned short* Qh  = wob + TW;   // [B*S][1024], pre-scaled
  unsigned short* Kh  = Qh + TA;    // [B*S][1024]
  unsigned short* Vt  = Kh + TA;    // [B,H,64,S]
  unsigned short* Cb  = Vt + TA;    // ctx bf16 [B*S][1024]

  cvt_all<<<dim3(14336), 256, 0, stream>>>(query, key, value, wq, wk, wv, wo,
                                           qb, kb, vb, wqb, wkb, wvb, wob);
  gemm_qkv<<<dim3(24, 64), 256, 0, stream>>>(qb, kb, vb, wqb, wkb, wvb,
                                             bq, bk, bv, Qh, Kh, Vt);
  attn_mfma<<<dim3(SEQ / 128, NHEAD, BATCH), 256, 0, stream>>>(Qh, Kh, Vt, Cb);
  gemm_out<<<dim3(8, 64), 256, 0, stream>>>(Cb, wob, bo, (float*)d_out);
}

// Round 4
// 388.521 us; speedup vs baseline: 1.4933x; 1.4933x over previous
//
#include <hip/hip_runtime.h>
#include <math.h>

#define D_MODEL 1024
#define NHEAD   16
#define DK      64
#define BATCH   4
#define SEQ     2048
#define MROWS   8192

typedef __attribute__((ext_vector_type(4)))  float f32x4;
typedef __attribute__((ext_vector_type(16))) float f32x16;
typedef __attribute__((ext_vector_type(8)))  short bf16x8;

// fold 1/sqrt(dk) * log2(e) into stored Q -> softmax runs in exp2 domain
#define QSCALE 0.18033688011112042f

__device__ __forceinline__ unsigned int cvt_pk_bf16(float lo, float hi) {
  unsigned int r;
  asm("v_cvt_pk_bf16_f32 %0, %1, %2" : "=v"(r) : "v"(lo), "v"(hi));
  return r;
}

// ---------------- fused fp32 -> bf16 convert, 7 segments ----------------
__global__ __launch_bounds__(256) void cvt_all(
    const float* __restrict__ q, const float* __restrict__ k, const float* __restrict__ v,
    const float* __restrict__ wq, const float* __restrict__ wk,
    const float* __restrict__ wv, const float* __restrict__ wo,
    unsigned short* __restrict__ qb, unsigned short* __restrict__ kb,
    unsigned short* __restrict__ vb, unsigned short* __restrict__ wqb,
    unsigned short* __restrict__ wkb, unsigned short* __restrict__ wvb,
    unsigned short* __restrict__ wob) {
  const int bid = blockIdx.x;
  const float* src; unsigned short* dst; int off;
  if      (bid < 4096)  { src = q;  dst = qb;  off = bid; }
  else if (bid < 8192)  { src = k;  dst = kb;  off = bid - 4096; }
  else if (bid < 12288) { src = v;  dst = vb;  off = bid - 8192; }
  else if (bid < 12800) { src = wq; dst = wqb; off = bid - 12288; }
  else if (bid < 13312) { src = wk; dst = wkb; off = bid - 12800; }
  else if (bid < 13824) { src = wv; dst = wvb; off = bid - 13312; }
  else                  { src = wo; dst = wob; off = bid - 13824; }
  const size_t i = (size_t)off * 256 + threadIdx.x;
  const float4* p = (const float4*)src + i * 2;
  const float4 a = p[0], b = p[1];
  int4 o;
  o.x = (int)cvt_pk_bf16(a.x, a.y);
  o.y = (int)cvt_pk_bf16(a.z, a.w);
  o.z = (int)cvt_pk_bf16(b.x, b.y);
  o.w = (int)cvt_pk_bf16(b.z, b.w);
  *(int4*)(dst + i * 8) = o;
}

// ---------------- fused QKV projection GEMM ----------------
// grid (24, 64): sector = blockIdx.x>>3 (0=Q,1=K,2=V). 128x128 tile, BK=32.
// Q/K out: bf16 [B,H,S,64] (Q pre-scaled by QSCALE). V out: [B,H,64,S].
__global__ __launch_bounds__(256) void gemm_qkv(
    const unsigned short* __restrict__ Aq, const unsigned short* __restrict__ Ak,
    const unsigned short* __restrict__ Av,
    const unsigned short* __restrict__ Wq, const unsigned short* __restrict__ Wk,
    const unsigned short* __restrict__ Wv,
    const float* __restrict__ bq, const float* __restrict__ bk,
    const float* __restrict__ bv,
    unsigned short* __restrict__ Qo, unsigned short* __restrict__ Ko,
    unsigned short* __restrict__ Vo) {
  __shared__ unsigned short Asb[128 * 32];
  __shared__ unsigned short Bsb[128 * 32];
  const int t = threadIdx.x;
  const int lane = t & 63, w = t >> 6;
  const int wr = w >> 1, wc = w & 1;
  const int g = lane >> 4, cl = lane & 15;
  const int sector = blockIdx.x >> 3;
  const int n0 = (blockIdx.x & 7) * 128;
  const int m0 = blockIdx.y * 128;
  const unsigned short* A = sector == 0 ? Aq : sector == 1 ? Ak : Av;
  const unsigned short* W = sector == 0 ? Wq : sector == 1 ? Wk : Wv;
  const float* bias = sector == 0 ? bq : sector == 1 ? bk : bv;

  f32x4 acc[4][4];
#pragma unroll
  for (int i = 0; i < 4; ++i)
#pragma unroll
    for (int j = 0; j < 4; ++j) acc[i][j] = (f32x4){0.f, 0.f, 0.f, 0.f};

  for (int k0 = 0; k0 < D_MODEL; k0 += 32) {
    __syncthreads();
#pragma unroll
    for (int p = 0; p < 2; ++p) {
      const int c = p * 256 + t;
      const unsigned short* ga = A + (size_t)(m0 + (c >> 2)) * D_MODEL + k0 + (c & 3) * 8;
      const unsigned short* gw = W + (size_t)(n0 + (c >> 2)) * D_MODEL + k0 + (c & 3) * 8;
      __builtin_amdgcn_global_load_lds(
          (const __attribute__((address_space(1))) unsigned int*)ga,
          (__attribute__((address_space(3))) unsigned int*)(Asb + (size_t)c * 8), 16, 0, 0);
      __builtin_amdgcn_global_load_lds(
          (const __attribute__((address_space(1))) unsigned int*)gw,
          (__attribute__((address_space(3))) unsigned int*)(Bsb + (size_t)c * 8), 16, 0, 0);
    }
    __syncthreads();

    bf16x8 af[4], bfr[4];
#pragma unroll
    for (int mi = 0; mi < 4; ++mi)
      af[mi] = *(const bf16x8*)&Asb[(wr * 64 + mi * 16 + cl) * 32 + g * 8];
#pragma unroll
    for (int ni = 0; ni < 4; ++ni)
      bfr[ni] = *(const bf16x8*)&Bsb[(wc * 64 + ni * 16 + cl) * 32 + g * 8];
#pragma unroll
    for (int mi = 0; mi < 4; ++mi)
#pragma unroll
      for (int ni = 0; ni < 4; ++ni)
        acc[mi][ni] = __builtin_amdgcn_mfma_f32_16x16x32_bf16(af[mi], bfr[ni], acc[mi][ni], 0, 0, 0);
  }

  if (sector < 2) {
    unsigned short* O = sector == 0 ? Qo : Ko;
    const float sc = sector == 0 ? QSCALE : 1.0f;
#pragma unroll
    for (int mi = 0; mi < 4; ++mi)
#pragma unroll
      for (int ni = 0; ni < 4; ++ni) {
        const int nn = n0 + wc * 64 + ni * 16 + cl;
        const int hh = nn >> 6, d = nn & 63;
        const float bvv = bias[nn];
#pragma unroll
        for (int j = 0; j < 4; ++j) {
          const int mm = m0 + wr * 64 + mi * 16 + 4 * g + j;
          const int b = mm >> 11, s = mm & (SEQ - 1);
          const float v = (acc[mi][ni][j] + bvv) * sc;
          O[(((size_t)(b * NHEAD + hh) * SEQ) + s) * DK + d] = (unsigned short)cvt_pk_bf16(v, v);
        }
      }
  } else {
#pragma unroll
    for (int mi = 0; mi < 4; ++mi)
#pragma unroll
      for (int ni = 0; ni < 4; ++ni) {
        const int nn = n0 + wc * 64 + ni * 16 + cl;
        const int hh = nn >> 6, d = nn & 63;
        const float bvv = bias[nn];
        const int mmb = m0 + wr * 64 + mi * 16 + 4 * g;
        const int b = mmb >> 11, s = mmb & (SEQ - 1);
        uint2 w2;
        w2.x = cvt_pk_bf16(acc[mi][ni][0] + bvv, acc[mi][ni][1] + bvv);
        w2.y = cvt_pk_bf16(acc[mi][ni][2] + bvv, acc[mi][ni][3] + bvv);
        *(uint2*)&Vo[(((size_t)(b * NHEAD + hh)) * DK + d) * SEQ + s] = w2;
      }
  }
}

// ---------------- output projection GEMM (bf16 in, fp32 out) ----------------
__global__ __launch_bounds__(256) void gemm_out(const unsigned short* __restrict__ A,
                                                const unsigned short* __restrict__ W,
                                                const float* __restrict__ bias,
                                                float* __restrict__ C) {
  __shared__ unsigned short Asb[128 * 32];
  __shared__ unsigned short Bsb[128 * 32];
  const int t = threadIdx.x;
  const int lane = t & 63, w = t >> 6;
  const int wr = w >> 1, wc = w & 1;
  const int g = lane >> 4, cl = lane & 15;
  const int m0 = blockIdx.y * 128, n0 = blockIdx.x * 128;

  f32x4 acc[4][4];
#pragma unroll
  for (int i = 0; i < 4; ++i)
#pragma unroll
    for (int j = 0; j < 4; ++j) acc[i][j] = (f32x4){0.f, 0.f, 0.f, 0.f};

  for (int k0 = 0; k0 < D_MODEL; k0 += 32) {
    __syncthreads();
#pragma unroll
    for (int p = 0; p < 2; ++p) {
      const int c = p * 256 + t;
      const unsigned short* ga = A + (size_t)(m0 + (c >> 2)) * D_MODEL + k0 + (c & 3) * 8;
      const unsigned short* gw = W + (size_t)(n0 + (c >> 2)) * D_MODEL + k0 + (c & 3) * 8;
      __builtin_amdgcn_global_load_lds(
          (const __attribute__((address_space(1))) unsigned int*)ga,
          (__attribute__((address_space(3))) unsigned int*)(Asb + (size_t)c * 8), 16, 0, 0);
      __builtin_amdgcn_global_load_lds(
          (const __attribute__((address_space(1))) unsigned int*)gw,
          (__attribute__((address_space(3))) unsigned int*)(Bsb + (size_t)c * 8), 16, 0, 0);
    }
    __syncthreads();

    bf16x8 af[4], bfr[4];
#pragma unroll
    for (int mi = 0; mi < 4; ++mi)
      af[mi] = *(const bf16x8*)&Asb[(wr * 64 + mi * 16 + cl) * 32 + g * 8];
#pragma unroll
    for (int ni = 0; ni < 4; ++ni)
      bfr[ni] = *(const bf16x8*)&Bsb[(wc * 64 + ni * 16 + cl) * 32 + g * 8];
#pragma unroll
    for (int mi = 0; mi < 4; ++mi)
#pragma unroll
      for (int ni = 0; ni < 4; ++ni)
        acc[mi][ni] = __builtin_amdgcn_mfma_f32_16x16x32_bf16(af[mi], bfr[ni], acc[mi][ni], 0, 0, 0);
  }

#pragma unroll
  for (int mi = 0; mi < 4; ++mi)
#pragma unroll
    for (int ni = 0; ni < 4; ++ni) {
      const int nn = n0 + wc * 64 + ni * 16 + cl;
      const float bvv = bias[nn];
#pragma unroll
      for (int j = 0; j < 4; ++j) {
        const int mm = m0 + wr * 64 + mi * 16 + 4 * g + j;
        C[(size_t)mm * D_MODEL + nn] = acc[mi][ni][j] + bvv;
      }
    }
}

// ---------------- Flash attention: swapped QK^T + LDS-staged K/V ----------------
// 4 waves/block, 32 q-rows/wave; K,V tiles (64 keys) staged in LDS via
// global_load_lds (16B), double-buffered, XOR-swizzled (pre-swizzled source +
// swizzled ds_read_b128, linear LDS dest). One __syncthreads per tile (its
// implied vmcnt(0) drains the async loads). Softmax fully in-register.
__global__ __launch_bounds__(256, 4) void attn_mfma(const unsigned short* __restrict__ Qh,
                                                    const unsigned short* __restrict__ Kh,
                                                    const unsigned short* __restrict__ Vt,
                                                    unsigned short* __restrict__ Ctx) {
  __shared__ unsigned short Ks[2][64 * 64];  // [buf][key][d] swizzled, 8KB each
  __shared__ unsigned short Vs[2][64 * 64];  // [buf][d][key] swizzled, 8KB each

  const int t = threadIdx.x;
  const int lane = t & 63, w = t >> 6;
  const int q32 = lane & 31, h = lane >> 5;
  const int xm = q32 & 7;
  const int head = blockIdx.y, b = blockIdx.z;
  const int q0 = blockIdx.x * 128 + w * 32;

  const unsigned short* Qp = Qh + ((size_t)(b * NHEAD + head) * SEQ + q0) * DK;
  const unsigned short* Kp = Kh + (size_t)(b * NHEAD + head) * SEQ * DK;
  const unsigned short* Vp = Vt + (size_t)(b * NHEAD + head) * DK * SEQ;

  // staging thread->chunk map (computed once): chunk cc = p*256+t of 512/tile
  int srow[2], ssl[2];
#pragma unroll
  for (int p = 0; p < 2; ++p) {
    const int cc = p * 256 + t;
    srow[p] = cc >> 3;
    ssl[p] = (cc & 7) ^ (srow[p] & 7);  // inverse swizzle on the SOURCE
  }

  // Q B-frags (loaded once): qf[dc] = Q[q0+q32][dc*16 + h*8 .. +7]
  bf16x8 qf[4];
#pragma unroll
  for (int dc = 0; dc < 4; ++dc)
    qf[dc] = *(const bf16x8*)&Qp[(size_t)q32 * DK + dc * 16 + h * 8];

  f32x16 oc[2];
#pragma unroll
  for (int d0 = 0; d0 < 2; ++d0)
#pragma unroll
    for (int r = 0; r < 16; ++r) oc[d0][r] = 0.f;
  float m = -1e30f, lsum = 0.f;

  // prologue: stage tile 0
#pragma unroll
  for (int p = 0; p < 2; ++p) {
    __builtin_amdgcn_global_load_lds(
        (const __attribute__((address_space(1))) unsigned int*)(Kp + (size_t)srow[p] * DK + ssl[p] * 8),
        (__attribute__((address_space(3))) unsigned int*)(&Ks[0][(p * 256 + t) * 8]), 16, 0, 0);
    __builtin_amdgcn_global_load_lds(
        (const __attribute__((address_space(1))) unsigned int*)(Vp + (size_t)srow[p] * SEQ + ssl[p] * 8),
        (__attribute__((address_space(3))) unsigned int*)(&Vs[0][(p * 256 + t) * 8]), 16, 0, 0);
  }
  __syncthreads();

  int cur = 0;
  for (int kt = 0; kt < SEQ / 64; ++kt) {
    // stage next tile into buf[cur^1] (async; drained by the barrier below)
    if (kt + 1 < SEQ / 64) {
      const int key1 = (kt + 1) * 64;
#pragma unroll
      for (int p = 0; p < 2; ++p) {
        __builtin_amdgcn_global_load_lds(
            (const __attribute__((address_space(1))) unsigned int*)(Kp + (size_t)(key1 + srow[p]) * DK + ssl[p] * 8),
            (__attribute__((address_space(3))) unsigned int*)(&Ks[cur ^ 1][(p * 256 + t) * 8]), 16, 0, 0);
        __builtin_amdgcn_global_load_lds(
            (const __attribute__((address_space(1))) unsigned int*)(Vp + (size_t)srow[p] * SEQ + key1 + ssl[p] * 8),
            (__attribute__((address_space(3))) unsigned int*)(&Vs[cur ^ 1][(p * 256 + t) * 8]), 16, 0, 0);
      }
    }

    const char* Kb = (const char*)&Ks[cur][0];
    const char* Vb = (const char*)&Vs[cur][0];

    // QK^T (swapped): st[kg] = S^T chunk, lane holds q=q32, 16 keys each
    f32x16 st[2];
    __builtin_amdgcn_s_setprio(1);
#pragma unroll
    for (int kg = 0; kg < 2; ++kg) {
#pragma unroll
      for (int r = 0; r < 16; ++r) st[kg][r] = 0.f;
#pragma unroll
      for (int dc = 0; dc < 4; ++dc) {
        const bf16x8 kf = *(const bf16x8*)(Kb + (kg * 32 + q32) * 128 + (((dc * 2 + h) ^ xm) << 4));
        st[kg] = __builtin_amdgcn_mfma_f32_32x32x16_bf16(kf, qf[dc], st[kg], 0, 0, 0);
      }
    }
    __builtin_amdgcn_s_setprio(0);

    // tile max (in-lane tree + partner exchange)
    float tmx[16];
#pragma unroll
    for (int r = 0; r < 16; ++r) tmx[r] = fmaxf(st[0][r], st[1][r]);
#pragma unroll
    for (int s = 8; s > 0; s >>= 1)
#pragma unroll
      for (int r = 0; r < 8; ++r)
        if (r < s) tmx[r] = fmaxf(tmx[r], tmx[r + s]);
    float pmax = fmaxf(tmx[0], __shfl_xor(tmx[0], 32));

    // defer-max rescale (wave-uniform branch)
    if (!__all(pmax - m <= 8.0f)) {
      const float mnew = fmaxf(m, pmax);
      const float fsc = exp2f(m - mnew);
      m = mnew;
      lsum *= fsc;
#pragma unroll
      for (int d0 = 0; d0 < 2; ++d0)
#pragma unroll
        for (int r = 0; r < 16; ++r) oc[d0][r] *= fsc;
    }

    // p = exp2(s - m); row-sum (own half)
    float rs[4] = {0.f, 0.f, 0.f, 0.f};
#pragma unroll
    for (int kg = 0; kg < 2; ++kg)
#pragma unroll
      for (int r = 0; r < 16; ++r) {
        const float p = exp2f(st[kg][r] - m);
        st[kg][r] = p;
        rs[r & 3] += p;
      }
    lsum += (rs[0] + rs[1]) + (rs[2] + rs[3]);

    // P -> bf16 PV fragments: 16 cvt_pk + 8 permlane32_swap
    unsigned int paw[4][4];
#pragma unroll
    for (int kg = 0; kg < 2; ++kg) {
      {
        auto s0 = __builtin_amdgcn_permlane32_swap(
            cvt_pk_bf16(st[kg][0], st[kg][1]), cvt_pk_bf16(st[kg][4], st[kg][5]), false, false);
        auto s1 = __builtin_amdgcn_permlane32_swap(
            cvt_pk_bf16(st[kg][2], st[kg][3]), cvt_pk_bf16(st[kg][6], st[kg][7]), false, false);
        paw[kg * 2][0] = s0[0]; paw[kg * 2][2] = s0[1];
        paw[kg * 2][1] = s1[0]; paw[kg * 2][3] = s1[1];
      }
      {
        auto s0 = __builtin_amdgcn_permlane32_swap(
            cvt_pk_bf16(st[kg][8], st[kg][9]), cvt_pk_bf16(st[kg][12], st[kg][13]), false, false);
        auto s1 = __builtin_amdgcn_permlane32_swap(
            cvt_pk_bf16(st[kg][10], st[kg][11]), cvt_pk_bf16(st[kg][14], st[kg][15]), false, false);
        paw[kg * 2 + 1][0] = s0[0]; paw[kg * 2 + 1][2] = s0[1];
        paw[kg * 2 + 1][1] = s1[0]; paw[kg * 2 + 1][3] = s1[1];
      }
    }

    // PV: oc[d0] += V^T_frag x P_frag (V from swizzled LDS)
    __builtin_amdgcn_s_setprio(1);
#pragma unroll
    for (int ks = 0; ks < 4; ++ks) {
      union { unsigned int u[4]; bf16x8 v; } pu;
      pu.u[0] = paw[ks][0]; pu.u[1] = paw[ks][1];
      pu.u[2] = paw[ks][2]; pu.u[3] = paw[ks][3];
#pragma unroll
      for (int d0 = 0; d0 < 2; ++d0) {
        const bf16x8 vf = *(const bf16x8*)(Vb + (d0 * 32 + q32) * 128 + (((ks * 2 + h) ^ xm) << 4));
        oc[d0] = __builtin_amdgcn_mfma_f32_32x32x16_bf16(vf, pu.v, oc[d0], 0, 0, 0);
      }
    }
    __builtin_amdgcn_s_setprio(0);

    __syncthreads();  // drains our async loads (vmcnt 0) + all waves done with buf[cur]
    cur ^= 1;
  }

  // epilogue: combine partner sums, normalize, pack 4 bf16 (8B) stores
  lsum += __shfl_xor(lsum, 32);
  const float inv = 1.f / lsum;
  unsigned short* Cp = Ctx + ((size_t)b * SEQ + q0 + q32) * D_MODEL + head * DK;
#pragma unroll
  for (int d0 = 0; d0 < 2; ++d0)
#pragma unroll
    for (int rq = 0; rq < 4; ++rq) {
      const int dbase = d0 * 32 + 8 * rq + 4 * h;
      uint2 w2;
      w2.x = cvt_pk_bf16(oc[d0][4 * rq + 0] * inv, oc[d0][4 * rq + 1] * inv);
      w2.y = cvt_pk_bf16(oc[d0][4 * rq + 2] * inv, oc[d0][4 * rq + 3] * inv);
      *(uint2*)(Cp + dbase) = w2;
    }
}

extern "C" void kernel_launch(void* const* d_in, const int* in_sizes, int n_in,
                              void* d_out, int out_size, void* d_ws, size_t ws_size,
                              hipStream_t stream) {
  const float* query = (const float*)d_in[0];
  const float* key   = (const float*)d_in[1];
  const float* value = (const float*)d_in[2];
  const float* wq = (const float*)d_in[3];
  const float* bq = (const float*)d_in[4];
  const float* wk = (const float*)d_in[5];
  const float* bk = (const float*)d_in[6];
  const float* wv = (const float*)d_in[7];
  const float* bv = (const float*)d_in[8];
  const float* wo = (const float*)d_in[9];
  const float* bo = (const float*)d_in[10];

  unsigned short* ws = (unsigned short*)d_ws;
  const size_t TA = (size_t)MROWS * D_MODEL;
  const size_t TW = (size_t)D_MODEL * D_MODEL;
  unsigned short* qb  = ws;
  unsigned short* kb  = qb + TA;
  unsigned short* vb  = kb + TA;
  unsigned short* wqb = vb + TA;
  unsigned short* wkb = wqb + TW;
  unsigned short* wvb = wkb + TW;
  unsigned short* wob = wvb + TW;
  unsigned short* Qh  = wob + TW;   // [B,H,S,64], pre-scaled
  unsigned short* Kh  = Qh + TA;    // [B,H,S,64]
  unsigned short* Vt  = Kh + TA;    // [B,H,64,S]
  unsigned short* Cb  = Vt + TA;    // ctx bf16 [B*S][1024]

  cvt_all<<<dim3(14336), 256, 0, stream>>>(query, key, value, wq, wk, wv, wo,
                                           qb, kb, vb, wqb, wkb, wvb, wob);
  gemm_qkv<<<dim3(24, 64), 256, 0, stream>>>(qb, kb, vb, wqb, wkb, wvb,
                                             bq, bk, bv, Qh, Kh, Vt);
  attn_mfma<<<dim3(SEQ / 128, NHEAD, BATCH), 256, 0, stream>>>(Qh, Kh, Vt, Cb);
  gemm_out<<<dim3(8, 64), 256, 0, stream>>>(Cb, wob, bo, (float*)d_out);
}

// Round 5
// 353.548 us; speedup vs baseline: 1.6411x; 1.0989x over previous
//
#include <hip/hip_runtime.h>
#include <math.h>

#define D_MODEL 1024
#define NHEAD   16
#define DK      64
#define BATCH   4
#define SEQ     2048
#define MROWS   8192

typedef __attribute__((ext_vector_type(4)))  float f32x4;
typedef __attribute__((ext_vector_type(16))) float f32x16;
typedef __attribute__((ext_vector_type(8)))  short bf16x8;

// fold 1/sqrt(dk) * log2(e) into stored Q -> softmax runs in exp2 domain
#define QSCALE 0.18033688011112042f

__device__ __forceinline__ unsigned int cvt_pk_bf16(float lo, float hi) {
  unsigned int r;
  asm("v_cvt_pk_bf16_f32 %0, %1, %2" : "=v"(r) : "v"(lo), "v"(hi));
  return r;
}

// ---------------- fused fp32 -> bf16 convert, 7 segments ----------------
__global__ __launch_bounds__(256) void cvt_all(
    const float* __restrict__ q, const float* __restrict__ k, const float* __restrict__ v,
    const float* __restrict__ wq, const float* __restrict__ wk,
    const float* __restrict__ wv, const float* __restrict__ wo,
    unsigned short* __restrict__ qb, unsigned short* __restrict__ kb,
    unsigned short* __restrict__ vb, unsigned short* __restrict__ wqb,
    unsigned short* __restrict__ wkb, unsigned short* __restrict__ wvb,
    unsigned short* __restrict__ wob) {
  const int bid = blockIdx.x;
  const float* src; unsigned short* dst; int off;
  if      (bid < 4096)  { src = q;  dst = qb;  off = bid; }
  else if (bid < 8192)  { src = k;  dst = kb;  off = bid - 4096; }
  else if (bid < 12288) { src = v;  dst = vb;  off = bid - 8192; }
  else if (bid < 12800) { src = wq; dst = wqb; off = bid - 12288; }
  else if (bid < 13312) { src = wk; dst = wkb; off = bid - 12800; }
  else if (bid < 13824) { src = wv; dst = wvb; off = bid - 13312; }
  else                  { src = wo; dst = wob; off = bid - 13824; }
  const size_t i = (size_t)off * 256 + threadIdx.x;
  const float4* p = (const float4*)src + i * 2;
  const float4 a = p[0], b = p[1];
  int4 o;
  o.x = (int)cvt_pk_bf16(a.x, a.y);
  o.y = (int)cvt_pk_bf16(a.z, a.w);
  o.z = (int)cvt_pk_bf16(b.x, b.y);
  o.w = (int)cvt_pk_bf16(b.z, b.w);
  *(int4*)(dst + i * 8) = o;
}

// ---------------- fused QKV projection GEMM ----------------
// 1-D grid 1536, XCD-chunked decode: same m-panel blocks land on one XCD.
// 128x128 tile, BK=32, 4 waves x 64x64 quadrant, 16x16x32 bf16 MFMA.
// Q/K out: bf16 [B,H,S,64] (Q pre-scaled). V out: [B,H,64,S].
__global__ __launch_bounds__(256) void gemm_qkv(
    const unsigned short* __restrict__ Aq, const unsigned short* __restrict__ Ak,
    const unsigned short* __restrict__ Av,
    const unsigned short* __restrict__ Wq, const unsigned short* __restrict__ Wk,
    const unsigned short* __restrict__ Wv,
    const float* __restrict__ bq, const float* __restrict__ bk,
    const float* __restrict__ bv,
    unsigned short* __restrict__ Qo, unsigned short* __restrict__ Ko,
    unsigned short* __restrict__ Vo) {
  __shared__ unsigned short Asb[128 * 32];
  __shared__ unsigned short Bsb[128 * 32];
  const int t = threadIdx.x;
  const int lane = t & 63, w = t >> 6;
  const int wr = w >> 1, wc = w & 1;
  const int g = lane >> 4, cl = lane & 15;
  // XCD-chunked decode (id%8 = XCD heuristic)
  const int id = blockIdx.x;
  const int jj = id >> 3;
  const int my = (id & 7) * 8 + (jj & 7);   // 0..63
  const int xs = jj >> 3;                   // 0..23
  const int sector = xs >> 3;
  const int n0 = (xs & 7) * 128;
  const int m0 = my * 128;
  const unsigned short* A = sector == 0 ? Aq : sector == 1 ? Ak : Av;
  const unsigned short* W = sector == 0 ? Wq : sector == 1 ? Wk : Wv;
  const float* bias = sector == 0 ? bq : sector == 1 ? bk : bv;

  f32x4 acc[4][4];
#pragma unroll
  for (int i = 0; i < 4; ++i)
#pragma unroll
    for (int j = 0; j < 4; ++j) acc[i][j] = (f32x4){0.f, 0.f, 0.f, 0.f};

  for (int k0 = 0; k0 < D_MODEL; k0 += 32) {
    __syncthreads();
#pragma unroll
    for (int p = 0; p < 2; ++p) {
      const int c = p * 256 + t;
      const unsigned short* ga = A + (size_t)(m0 + (c >> 2)) * D_MODEL + k0 + (c & 3) * 8;
      const unsigned short* gw = W + (size_t)(n0 + (c >> 2)) * D_MODEL + k0 + (c & 3) * 8;
      __builtin_amdgcn_global_load_lds(
          (const __attribute__((address_space(1))) unsigned int*)ga,
          (__attribute__((address_space(3))) unsigned int*)(Asb + (size_t)c * 8), 16, 0, 0);
      __builtin_amdgcn_global_load_lds(
          (const __attribute__((address_space(1))) unsigned int*)gw,
          (__attribute__((address_space(3))) unsigned int*)(Bsb + (size_t)c * 8), 16, 0, 0);
    }
    __syncthreads();

    bf16x8 af[4], bfr[4];
#pragma unroll
    for (int mi = 0; mi < 4; ++mi)
      af[mi] = *(const bf16x8*)&Asb[(wr * 64 + mi * 16 + cl) * 32 + g * 8];
#pragma unroll
    for (int ni = 0; ni < 4; ++ni)
      bfr[ni] = *(const bf16x8*)&Bsb[(wc * 64 + ni * 16 + cl) * 32 + g * 8];
#pragma unroll
    for (int mi = 0; mi < 4; ++mi)
#pragma unroll
      for (int ni = 0; ni < 4; ++ni)
        acc[mi][ni] = __builtin_amdgcn_mfma_f32_16x16x32_bf16(af[mi], bfr[ni], acc[mi][ni], 0, 0, 0);
  }

  if (sector < 2) {
    unsigned short* O = sector == 0 ? Qo : Ko;
    const float sc = sector == 0 ? QSCALE : 1.0f;
#pragma unroll
    for (int mi = 0; mi < 4; ++mi)
#pragma unroll
      for (int ni = 0; ni < 4; ++ni) {
        const int nn = n0 + wc * 64 + ni * 16 + cl;
        const int hh = nn >> 6, d = nn & 63;
        const float bvv = bias[nn];
#pragma unroll
        for (int j = 0; j < 4; ++j) {
          const int mm = m0 + wr * 64 + mi * 16 + 4 * g + j;
          const int b = mm >> 11, s = mm & (SEQ - 1);
          const float v = (acc[mi][ni][j] + bvv) * sc;
          O[(((size_t)(b * NHEAD + hh) * SEQ) + s) * DK + d] = (unsigned short)cvt_pk_bf16(v, v);
        }
      }
  } else {
#pragma unroll
    for (int mi = 0; mi < 4; ++mi)
#pragma unroll
      for (int ni = 0; ni < 4; ++ni) {
        const int nn = n0 + wc * 64 + ni * 16 + cl;
        const int hh = nn >> 6, d = nn & 63;
        const float bvv = bias[nn];
        const int mmb = m0 + wr * 64 + mi * 16 + 4 * g;
        const int b = mmb >> 11, s = mmb & (SEQ - 1);
        uint2 w2;
        w2.x = cvt_pk_bf16(acc[mi][ni][0] + bvv, acc[mi][ni][1] + bvv);
        w2.y = cvt_pk_bf16(acc[mi][ni][2] + bvv, acc[mi][ni][3] + bvv);
        *(uint2*)&Vo[(((size_t)(b * NHEAD + hh)) * DK + d) * SEQ + s] = w2;
      }
  }
}

// ---------------- output projection GEMM (bf16 in, fp32 out) ----------------
__global__ __launch_bounds__(256) void gemm_out(const unsigned short* __restrict__ A,
                                                const unsigned short* __restrict__ W,
                                                const float* __restrict__ bias,
                                                float* __restrict__ C) {
  __shared__ unsigned short Asb[128 * 32];
  __shared__ unsigned short Bsb[128 * 32];
  const int t = threadIdx.x;
  const int lane = t & 63, w = t >> 6;
  const int wr = w >> 1, wc = w & 1;
  const int g = lane >> 4, cl = lane & 15;
  const int id = blockIdx.x;
  const int jj = id >> 3;
  const int my = (id & 7) * 8 + (jj & 7);   // 0..63
  const int m0 = my * 128, n0 = (jj >> 3) * 128;

  f32x4 acc[4][4];
#pragma unroll
  for (int i = 0; i < 4; ++i)
#pragma unroll
    for (int j = 0; j < 4; ++j) acc[i][j] = (f32x4){0.f, 0.f, 0.f, 0.f};

  for (int k0 = 0; k0 < D_MODEL; k0 += 32) {
    __syncthreads();
#pragma unroll
    for (int p = 0; p < 2; ++p) {
      const int c = p * 256 + t;
      const unsigned short* ga = A + (size_t)(m0 + (c >> 2)) * D_MODEL + k0 + (c & 3) * 8;
      const unsigned short* gw = W + (size_t)(n0 + (c >> 2)) * D_MODEL + k0 + (c & 3) * 8;
      __builtin_amdgcn_global_load_lds(
          (const __attribute__((address_space(1))) unsigned int*)ga,
          (__attribute__((address_space(3))) unsigned int*)(Asb + (size_t)c * 8), 16, 0, 0);
      __builtin_amdgcn_global_load_lds(
          (const __attribute__((address_space(1))) unsigned int*)gw,
          (__attribute__((address_space(3))) unsigned int*)(Bsb + (size_t)c * 8), 16, 0, 0);
    }
    __syncthreads();

    bf16x8 af[4], bfr[4];
#pragma unroll
    for (int mi = 0; mi < 4; ++mi)
      af[mi] = *(const bf16x8*)&Asb[(wr * 64 + mi * 16 + cl) * 32 + g * 8];
#pragma unroll
    for (int ni = 0; ni < 4; ++ni)
      bfr[ni] = *(const bf16x8*)&Bsb[(wc * 64 + ni * 16 + cl) * 32 + g * 8];
#pragma unroll
    for (int mi = 0; mi < 4; ++mi)
#pragma unroll
      for (int ni = 0; ni < 4; ++ni)
        acc[mi][ni] = __builtin_amdgcn_mfma_f32_16x16x32_bf16(af[mi], bfr[ni], acc[mi][ni], 0, 0, 0);
  }

#pragma unroll
  for (int mi = 0; mi < 4; ++mi)
#pragma unroll
    for (int ni = 0; ni < 4; ++ni) {
      const int nn = n0 + wc * 64 + ni * 16 + cl;
      const float bvv = bias[nn];
#pragma unroll
      for (int j = 0; j < 4; ++j) {
        const int mm = m0 + wr * 64 + mi * 16 + 4 * g + j;
        C[(size_t)mm * D_MODEL + nn] = acc[mi][ni][j] + bvv;
      }
    }
}

// ---------------- Flash attention: swapped QK^T + LDS-staged K/V ----------------
// 1-D grid 1024, XCD-chunked: all 16 q-tiles of one (b,h) on one XCD (K/V L2-resident).
// 4 waves/block, 32 q-rows/wave; K,V tiles double-buffered in LDS via global_load_lds,
// XOR-swizzled (pre-swizzled source, linear dest, swizzled ds_read_b128).
// kt-loop manually unrolled x2 -> compile-time buffer parity, immediate LDS offsets.
__global__ __launch_bounds__(256) void attn_mfma(const unsigned short* __restrict__ Qh,
                                                 const unsigned short* __restrict__ Kh,
                                                 const unsigned short* __restrict__ Vt,
                                                 unsigned short* __restrict__ Ctx) {
  __shared__ unsigned short Ks[2][64 * 64];  // [buf][key][d] swizzled, 8KB each
  __shared__ unsigned short Vs[2][64 * 64];  // [buf][d][key] swizzled, 8KB each

  const int t = threadIdx.x;
  const int lane = t & 63, w = t >> 6;
  const int q32 = lane & 31, h = lane >> 5;
  const int xm = q32 & 7;

  // XCD-chunked decode: id%8 selects XCD; each XCD owns 8 (b,h) pairs.
  const int id = blockIdx.x;
  const int jj = id >> 3;
  const int bh = (id & 7) * 8 + (jj & 7);   // 0..63 = b*NHEAD + head
  const int qt = jj >> 3;                   // 0..15
  const int q0 = qt * 128 + w * 32;

  const unsigned short* Qp = Qh + ((size_t)bh * SEQ + q0) * DK;
  const unsigned short* Kp = Kh + (size_t)bh * SEQ * DK;
  const unsigned short* Vp = Vt + (size_t)bh * DK * SEQ;

  // staging map: chunk cc (0..511) -> LDS 16B slot cc, global slot (cc&7)^(row&7)
  const int cc0 = t, cc1 = 256 + t;
  const int sr0 = cc0 >> 3, sr1 = cc1 >> 3;
  const unsigned short* kp0 = Kp + sr0 * DK  + (((cc0 & 7) ^ (sr0 & 7)) << 3);
  const unsigned short* kp1 = Kp + sr1 * DK  + (((cc1 & 7) ^ (sr1 & 7)) << 3);
  const unsigned short* vp0 = Vp + sr0 * SEQ + (((cc0 & 7) ^ (sr0 & 7)) << 3);
  const unsigned short* vp1 = Vp + sr1 * SEQ + (((cc1 & 7) ^ (sr1 & 7)) << 3);

  auto stage = [&](int buf) {
    __builtin_amdgcn_global_load_lds(
        (const __attribute__((address_space(1))) unsigned int*)kp0,
        (__attribute__((address_space(3))) unsigned int*)(&Ks[buf][cc0 * 8]), 16, 0, 0);
    __builtin_amdgcn_global_load_lds(
        (const __attribute__((address_space(1))) unsigned int*)kp1,
        (__attribute__((address_space(3))) unsigned int*)(&Ks[buf][cc1 * 8]), 16, 0, 0);
    __builtin_amdgcn_global_load_lds(
        (const __attribute__((address_space(1))) unsigned int*)vp0,
        (__attribute__((address_space(3))) unsigned int*)(&Vs[buf][cc0 * 8]), 16, 0, 0);
    __builtin_amdgcn_global_load_lds(
        (const __attribute__((address_space(1))) unsigned int*)vp1,
        (__attribute__((address_space(3))) unsigned int*)(&Vs[buf][cc1 * 8]), 16, 0, 0);
    kp0 += 64 * DK; kp1 += 64 * DK;   // next 64 keys
    vp0 += 64;      vp1 += 64;        // next 64 keys (keys contiguous in Vt rows)
  };

  // Q B-frags (loaded once)
  bf16x8 qf[4];
#pragma unroll
  for (int dc = 0; dc < 4; ++dc)
    qf[dc] = *(const bf16x8*)&Qp[(size_t)q32 * DK + dc * 16 + h * 8];

  f32x16 oc[2];
#pragma unroll
  for (int d0 = 0; d0 < 2; ++d0)
#pragma unroll
    for (int r = 0; r < 16; ++r) oc[d0][r] = 0.f;
  float m = -1e30f, lsum = 0.f;

  auto compute = [&](int buf) {
    const char* Kb = (const char*)&Ks[buf][0];
    const char* Vb = (const char*)&Vs[buf][0];

    // QK^T (swapped): lane holds q=q32; st0/st1 = 16 keys each per half
    f32x16 st0, st1;
#pragma unroll
    for (int r = 0; r < 16; ++r) { st0[r] = 0.f; st1[r] = 0.f; }
    __builtin_amdgcn_s_setprio(1);
#pragma unroll
    for (int dc = 0; dc < 4; ++dc) {
      const bf16x8 kf0 = *(const bf16x8*)(Kb + (q32)*128      + (((dc * 2 + h) ^ xm) << 4));
      st0 = __builtin_amdgcn_mfma_f32_32x32x16_bf16(kf0, qf[dc], st0, 0, 0, 0);
      const bf16x8 kf1 = *(const bf16x8*)(Kb + (32 + q32)*128 + (((dc * 2 + h) ^ xm) << 4));
      st1 = __builtin_amdgcn_mfma_f32_32x32x16_bf16(kf1, qf[dc], st1, 0, 0, 0);
    }
    __builtin_amdgcn_s_setprio(0);

    // row max (v_max3-friendly tree) + partner exchange
    float tmx[8];
#pragma unroll
    for (int r = 0; r < 8; ++r)
      tmx[r] = fmaxf(fmaxf(st0[r], st0[r + 8]), fmaxf(st1[r], st1[r + 8]));
    const float a0 = fmaxf(fmaxf(tmx[0], tmx[1]), tmx[2]);
    const float a1 = fmaxf(fmaxf(tmx[3], tmx[4]), tmx[5]);
    const float a2 = fmaxf(tmx[6], tmx[7]);
    float pmax = fmaxf(fmaxf(a0, a1), a2);
    pmax = fmaxf(pmax, __shfl_xor(pmax, 32));

    // defer-max rescale (wave-uniform branch, THR=8 in log2 domain)
    if (!__all(pmax - m <= 8.0f)) {
      const float mnew = fmaxf(m, pmax);
      const float fsc = __builtin_amdgcn_exp2f(m - mnew);
      m = mnew;
      lsum *= fsc;
#pragma unroll
      for (int d0 = 0; d0 < 2; ++d0)
#pragma unroll
        for (int r = 0; r < 16; ++r) oc[d0][r] *= fsc;
    }

    // p = exp2(s - m); row-sum (own half)
    float rs0 = 0.f, rs1 = 0.f, rs2 = 0.f, rs3 = 0.f;
#pragma unroll
    for (int r = 0; r < 16; ++r) {
      const float p0 = __builtin_amdgcn_exp2f(st0[r] - m);
      st0[r] = p0;
      const float p1 = __builtin_amdgcn_exp2f(st1[r] - m);
      st1[r] = p1;
      if ((r & 3) == 0) rs0 += p0 + p1;
      else if ((r & 3) == 1) rs1 += p0 + p1;
      else if ((r & 3) == 2) rs2 += p0 + p1;
      else rs3 += p0 + p1;
    }
    lsum += (rs0 + rs1) + (rs2 + rs3);

    // P -> bf16 PV fragments: 16 cvt_pk + 8 permlane32_swap, assembled as int4
    int4 pv[4];
    {
      auto s0 = __builtin_amdgcn_permlane32_swap(
          cvt_pk_bf16(st0[0], st0[1]), cvt_pk_bf16(st0[4], st0[5]), false, false);
      auto s1 = __builtin_amdgcn_permlane32_swap(
          cvt_pk_bf16(st0[2], st0[3]), cvt_pk_bf16(st0[6], st0[7]), false, false);
      pv[0] = (int4){(int)s0[0], (int)s1[0], (int)s0[1], (int)s1[1]};
      auto s2 = __builtin_amdgcn_permlane32_swap(
          cvt_pk_bf16(st0[8], st0[9]), cvt_pk_bf16(st0[12], st0[13]), false, false);
      auto s3 = __builtin_amdgcn_permlane32_swap(
          cvt_pk_bf16(st0[10], st0[11]), cvt_pk_bf16(st0[14], st0[15]), false, false);
      pv[1] = (int4){(int)s2[0], (int)s3[0], (int)s2[1], (int)s3[1]};
      auto s4 = __builtin_amdgcn_permlane32_swap(
          cvt_pk_bf16(st1[0], st1[1]), cvt_pk_bf16(st1[4], st1[5]), false, false);
      auto s5 = __builtin_amdgcn_permlane32_swap(
          cvt_pk_bf16(st1[2], st1[3]), cvt_pk_bf16(st1[6], st1[7]), false, false);
      pv[2] = (int4){(int)s4[0], (int)s5[0], (int)s4[1], (int)s5[1]};
      auto s6 = __builtin_amdgcn_permlane32_swap(
          cvt_pk_bf16(st1[8], st1[9]), cvt_pk_bf16(st1[12], st1[13]), false, false);
      auto s7 = __builtin_amdgcn_permlane32_swap(
          cvt_pk_bf16(st1[10], st1[11]), cvt_pk_bf16(st1[14], st1[15]), false, false);
      pv[3] = (int4){(int)s6[0], (int)s7[0], (int)s6[1], (int)s7[1]};
    }

    // PV: oc[d0] += V^T_frag x P_frag (V from swizzled LDS)
    __builtin_amdgcn_s_setprio(1);
#pragma unroll
    for (int ks = 0; ks < 4; ++ks) {
      union { int4 i; bf16x8 v; } pu;
      pu.i = pv[ks];
#pragma unroll
      for (int d0 = 0; d0 < 2; ++d0) {
        const bf16x8 vf = *(const bf16x8*)(Vb + (d0 * 32 + q32) * 128 + (((ks * 2 + h) ^ xm) << 4));
        oc[d0] = __builtin_amdgcn_mfma_f32_32x32x16_bf16(vf, pu.v, oc[d0], 0, 0, 0);
      }
    }
    __builtin_amdgcn_s_setprio(0);
  };

  // pipeline: stage(next) before compute(cur); one barrier/tile drains async loads
  stage(0);
  __syncthreads();
#pragma unroll 1
  for (int kt = 0; kt < 30; kt += 2) {
    stage(1);
    compute(0);
    __syncthreads();
    stage(0);
    compute(1);
    __syncthreads();
  }
  stage(1);      // tile 31
  compute(0);    // tile 30
  __syncthreads();
  compute(1);    // tile 31

  // epilogue: combine partner sums, normalize, pack 4 bf16 (8B) stores
  lsum += __shfl_xor(lsum, 32);
  const float inv = 1.f / lsum;
  unsigned short* Cp = Ctx + ((size_t)(bh >> 4) * SEQ + q0 + q32) * D_MODEL + (bh & 15) * DK;
#pragma unroll
  for (int d0 = 0; d0 < 2; ++d0)
#pragma unroll
    for (int rq = 0; rq < 4; ++rq) {
      const int dbase = d0 * 32 + 8 * rq + 4 * h;
      uint2 w2;
      w2.x = cvt_pk_bf16(oc[d0][4 * rq + 0] * inv, oc[d0][4 * rq + 1] * inv);
      w2.y = cvt_pk_bf16(oc[d0][4 * rq + 2] * inv, oc[d0][4 * rq + 3] * inv);
      *(uint2*)(Cp + dbase) = w2;
    }
}

extern "C" void kernel_launch(void* const* d_in, const int* in_sizes, int n_in,
                              void* d_out, int out_size, void* d_ws, size_t ws_size,
                              hipStream_t stream) {
  const float* query = (const float*)d_in[0];
  const float* key   = (const float*)d_in[1];
  const float* value = (const float*)d_in[2];
  const float* wq = (const float*)d_in[3];
  const float* bq = (const float*)d_in[4];
  const float* wk = (const float*)d_in[5];
  const float* bk = (const float*)d_in[6];
  const float* wv = (const float*)d_in[7];
  const float* bv = (const float*)d_in[8];
  const float* wo = (const float*)d_in[9];
  const float* bo = (const float*)d_in[10];

  unsigned short* ws = (unsigned short*)d_ws;
  const size_t TA = (size_t)MROWS * D_MODEL;
  const size_t TW = (size_t)D_MODEL * D_MODEL;
  unsigned short* qb  = ws;
  unsigned short* kb  = qb + TA;
  unsigned short* vb  = kb + TA;
  unsigned short* wqb = vb + TA;
  unsigned short* wkb = wqb + TW;
  unsigned short* wvb = wkb + TW;
  unsigned short* wob = wvb + TW;
  unsigned short* Qh  = wob + TW;   // [B,H,S,64], pre-scaled
  unsigned short* Kh  = Qh + TA;    // [B,H,S,64]
  unsigned short* Vt  = Kh + TA;    // [B,H,64,S]
  unsigned short* Cb  = Vt + TA;    // ctx bf16 [B*S][1024]

  cvt_all<<<dim3(14336), 256, 0, stream>>>(query, key, value, wq, wk, wv, wo,
                                           qb, kb, vb, wqb, wkb, wvb, wob);
  gemm_qkv<<<dim3(1536), 256, 0, stream>>>(qb, kb, vb, wqb, wkb, wvb,
                                           bq, bk, bv, Qh, Kh, Vt);
  attn_mfma<<<dim3(1024), 256, 0, stream>>>(Qh, Kh, Vt, Cb);
  gemm_out<<<dim3(512), 256, 0, stream>>>(Cb, wob, bo, (float*)d_out);
}

// Round 6
// 352.896 us; speedup vs baseline: 1.6441x; 1.0018x over previous
//
#include <hip/hip_runtime.h>
#include <math.h>

#define D_MODEL 1024
#define NHEAD   16
#define DK      64
#define BATCH   4
#define SEQ     2048
#define MROWS   8192

typedef __attribute__((ext_vector_type(4)))  float f32x4;
typedef __attribute__((ext_vector_type(16))) float f32x16;
typedef __attribute__((ext_vector_type(8)))  short bf16x8;

// fold 1/sqrt(dk) * log2(e) into stored Q -> softmax runs in exp2 domain
#define QSCALE 0.18033688011112042f

__device__ __forceinline__ unsigned int cvt_pk_bf16(float lo, float hi) {
  unsigned int r;
  asm("v_cvt_pk_bf16_f32 %0, %1, %2" : "=v"(r) : "v"(lo), "v"(hi));
  return r;
}

// ---------------- fused fp32 -> bf16 convert, 7 segments ----------------
__global__ __launch_bounds__(256) void cvt_all(
    const float* __restrict__ q, const float* __restrict__ k, const float* __restrict__ v,
    const float* __restrict__ wq, const float* __restrict__ wk,
    const float* __restrict__ wv, const float* __restrict__ wo,
    unsigned short* __restrict__ qb, unsigned short* __restrict__ kb,
    unsigned short* __restrict__ vb, unsigned short* __restrict__ wqb,
    unsigned short* __restrict__ wkb, unsigned short* __restrict__ wvb,
    unsigned short* __restrict__ wob) {
  const int bid = blockIdx.x;
  const float* src; unsigned short* dst; int off;
  if      (bid < 4096)  { src = q;  dst = qb;  off = bid; }
  else if (bid < 8192)  { src = k;  dst = kb;  off = bid - 4096; }
  else if (bid < 12288) { src = v;  dst = vb;  off = bid - 8192; }
  else if (bid < 12800) { src = wq; dst = wqb; off = bid - 12288; }
  else if (bid < 13312) { src = wk; dst = wkb; off = bid - 12800; }
  else if (bid < 13824) { src = wv; dst = wvb; off = bid - 13312; }
  else                  { src = wo; dst = wob; off = bid - 13824; }
  const size_t i = (size_t)off * 256 + threadIdx.x;
  const float4* p = (const float4*)src + i * 2;
  const float4 a = p[0], b = p[1];
  int4 o;
  o.x = (int)cvt_pk_bf16(a.x, a.y);
  o.y = (int)cvt_pk_bf16(a.z, a.w);
  o.z = (int)cvt_pk_bf16(b.x, b.y);
  o.w = (int)cvt_pk_bf16(b.z, b.w);
  *(int4*)(dst + i * 8) = o;
}

// ---------------- fused QKV projection GEMM ----------------
// 1-D grid 1536, XCD-chunked decode. 128x128 tile, BK=32, 4 waves x 64x64.
// Q/K out: bf16 [B,H,S,64] (Q pre-scaled). V out: [B,H,64,S].
__global__ __launch_bounds__(256) void gemm_qkv(
    const unsigned short* __restrict__ Aq, const unsigned short* __restrict__ Ak,
    const unsigned short* __restrict__ Av,
    const unsigned short* __restrict__ Wq, const unsigned short* __restrict__ Wk,
    const unsigned short* __restrict__ Wv,
    const float* __restrict__ bq, const float* __restrict__ bk,
    const float* __restrict__ bv,
    unsigned short* __restrict__ Qo, unsigned short* __restrict__ Ko,
    unsigned short* __restrict__ Vo) {
  __shared__ unsigned short Asb[128 * 32];
  __shared__ unsigned short Bsb[128 * 32];
  const int t = threadIdx.x;
  const int lane = t & 63, w = t >> 6;
  const int wr = w >> 1, wc = w & 1;
  const int g = lane >> 4, cl = lane & 15;
  const int id = blockIdx.x;
  const int jj = id >> 3;
  const int my = (id & 7) * 8 + (jj & 7);   // 0..63
  const int xs = jj >> 3;                   // 0..23
  const int sector = xs >> 3;
  const int n0 = (xs & 7) * 128;
  const int m0 = my * 128;
  const unsigned short* A = sector == 0 ? Aq : sector == 1 ? Ak : Av;
  const unsigned short* W = sector == 0 ? Wq : sector == 1 ? Wk : Wv;
  const float* bias = sector == 0 ? bq : sector == 1 ? bk : bv;

  f32x4 acc[4][4];
#pragma unroll
  for (int i = 0; i < 4; ++i)
#pragma unroll
    for (int j = 0; j < 4; ++j) acc[i][j] = (f32x4){0.f, 0.f, 0.f, 0.f};

  for (int k0 = 0; k0 < D_MODEL; k0 += 32) {
    __syncthreads();
#pragma unroll
    for (int p = 0; p < 2; ++p) {
      const int c = p * 256 + t;
      const unsigned short* ga = A + (size_t)(m0 + (c >> 2)) * D_MODEL + k0 + (c & 3) * 8;
      const unsigned short* gw = W + (size_t)(n0 + (c >> 2)) * D_MODEL + k0 + (c & 3) * 8;
      __builtin_amdgcn_global_load_lds(
          (const __attribute__((address_space(1))) unsigned int*)ga,
          (__attribute__((address_space(3))) unsigned int*)(Asb + (size_t)c * 8), 16, 0, 0);
      __builtin_amdgcn_global_load_lds(
          (const __attribute__((address_space(1))) unsigned int*)gw,
          (__attribute__((address_space(3))) unsigned int*)(Bsb + (size_t)c * 8), 16, 0, 0);
    }
    __syncthreads();

    bf16x8 af[4], bfr[4];
#pragma unroll
    for (int mi = 0; mi < 4; ++mi)
      af[mi] = *(const bf16x8*)&Asb[(wr * 64 + mi * 16 + cl) * 32 + g * 8];
#pragma unroll
    for (int ni = 0; ni < 4; ++ni)
      bfr[ni] = *(const bf16x8*)&Bsb[(wc * 64 + ni * 16 + cl) * 32 + g * 8];
#pragma unroll
    for (int mi = 0; mi < 4; ++mi)
#pragma unroll
      for (int ni = 0; ni < 4; ++ni)
        acc[mi][ni] = __builtin_amdgcn_mfma_f32_16x16x32_bf16(af[mi], bfr[ni], acc[mi][ni], 0, 0, 0);
  }

  if (sector < 2) {
    unsigned short* O = sector == 0 ? Qo : Ko;
    const float sc = sector == 0 ? QSCALE : 1.0f;
#pragma unroll
    for (int mi = 0; mi < 4; ++mi)
#pragma unroll
      for (int ni = 0; ni < 4; ++ni) {
        const int nn = n0 + wc * 64 + ni * 16 + cl;
        const int hh = nn >> 6, d = nn & 63;
        const float bvv = bias[nn];
#pragma unroll
        for (int j = 0; j < 4; ++j) {
          const int mm = m0 + wr * 64 + mi * 16 + 4 * g + j;
          const int b = mm >> 11, s = mm & (SEQ - 1);
          const float v = (acc[mi][ni][j] + bvv) * sc;
          O[(((size_t)(b * NHEAD + hh) * SEQ) + s) * DK + d] = (unsigned short)cvt_pk_bf16(v, v);
        }
      }
  } else {
#pragma unroll
    for (int mi = 0; mi < 4; ++mi)
#pragma unroll
      for (int ni = 0; ni < 4; ++ni) {
        const int nn = n0 + wc * 64 + ni * 16 + cl;
        const int hh = nn >> 6, d = nn & 63;
        const float bvv = bias[nn];
        const int mmb = m0 + wr * 64 + mi * 16 + 4 * g;
        const int b = mmb >> 11, s = mmb & (SEQ - 1);
        uint2 w2;
        w2.x = cvt_pk_bf16(acc[mi][ni][0] + bvv, acc[mi][ni][1] + bvv);
        w2.y = cvt_pk_bf16(acc[mi][ni][2] + bvv, acc[mi][ni][3] + bvv);
        *(uint2*)&Vo[(((size_t)(b * NHEAD + hh)) * DK + d) * SEQ + s] = w2;
      }
  }
}

// ---------------- output projection GEMM (bf16 in, fp32 out) ----------------
__global__ __launch_bounds__(256) void gemm_out(const unsigned short* __restrict__ A,
                                                const unsigned short* __restrict__ W,
                                                const float* __restrict__ bias,
                                                float* __restrict__ C) {
  __shared__ unsigned short Asb[128 * 32];
  __shared__ unsigned short Bsb[128 * 32];
  const int t = threadIdx.x;
  const int lane = t & 63, w = t >> 6;
  const int wr = w >> 1, wc = w & 1;
  const int g = lane >> 4, cl = lane & 15;
  const int id = blockIdx.x;
  const int jj = id >> 3;
  const int my = (id & 7) * 8 + (jj & 7);   // 0..63
  const int m0 = my * 128, n0 = (jj >> 3) * 128;

  f32x4 acc[4][4];
#pragma unroll
  for (int i = 0; i < 4; ++i)
#pragma unroll
    for (int j = 0; j < 4; ++j) acc[i][j] = (f32x4){0.f, 0.f, 0.f, 0.f};

  for (int k0 = 0; k0 < D_MODEL; k0 += 32) {
    __syncthreads();
#pragma unroll
    for (int p = 0; p < 2; ++p) {
      const int c = p * 256 + t;
      const unsigned short* ga = A + (size_t)(m0 + (c >> 2)) * D_MODEL + k0 + (c & 3) * 8;
      const unsigned short* gw = W + (size_t)(n0 + (c >> 2)) * D_MODEL + k0 + (c & 3) * 8;
      __builtin_amdgcn_global_load_lds(
          (const __attribute__((address_space(1))) unsigned int*)ga,
          (__attribute__((address_space(3))) unsigned int*)(Asb + (size_t)c * 8), 16, 0, 0);
      __builtin_amdgcn_global_load_lds(
          (const __attribute__((address_space(1))) unsigned int*)gw,
          (__attribute__((address_space(3))) unsigned int*)(Bsb + (size_t)c * 8), 16, 0, 0);
    }
    __syncthreads();

    bf16x8 af[4], bfr[4];
#pragma unroll
    for (int mi = 0; mi < 4; ++mi)
      af[mi] = *(const bf16x8*)&Asb[(wr * 64 + mi * 16 + cl) * 32 + g * 8];
#pragma unroll
    for (int ni = 0; ni < 4; ++ni)
      bfr[ni] = *(const bf16x8*)&Bsb[(wc * 64 + ni * 16 + cl) * 32 + g * 8];
#pragma unroll
    for (int mi = 0; mi < 4; ++mi)
#pragma unroll
      for (int ni = 0; ni < 4; ++ni)
        acc[mi][ni] = __builtin_amdgcn_mfma_f32_16x16x32_bf16(af[mi], bfr[ni], acc[mi][ni], 0, 0, 0);
  }

#pragma unroll
  for (int mi = 0; mi < 4; ++mi)
#pragma unroll
    for (int ni = 0; ni < 4; ++ni) {
      const int nn = n0 + wc * 64 + ni * 16 + cl;
      const float bvv = bias[nn];
#pragma unroll
      for (int j = 0; j < 4; ++j) {
        const int mm = m0 + wr * 64 + mi * 16 + 4 * g + j;
        C[(size_t)mm * D_MODEL + nn] = acc[mi][ni][j] + bvv;
      }
    }
}

// ---------------- Flash attention: T15 two-tile pipeline ----------------
// 1-D grid 1024, XCD-chunked (K/V L2-resident). 4 waves/block, 32 q-rows/wave.
// 3 LDS buffers, prefetch 2 tiles ahead; per tile: stage(t+2) -> QK(t+1)->stB
// -> softmax(t)+PV(t) from stA -> barrier. QK MFMAs of t+1 execute under the
// softmax VALU of t (intra-wave MFMA/VALU overlap). 6-unrolled for static %2/%3.
__global__ __launch_bounds__(256) void attn_mfma(const unsigned short* __restrict__ Qh,
                                                 const unsigned short* __restrict__ Kh,
                                                 const unsigned short* __restrict__ Vt,
                                                 unsigned short* __restrict__ Ctx) {
  __shared__ unsigned short Ks[3][64 * 64];  // [buf][key][d] swizzled, 8KB each
  __shared__ unsigned short Vs[3][64 * 64];  // [buf][d][key] swizzled, 8KB each

  const int t = threadIdx.x;
  const int lane = t & 63, w = t >> 6;
  const int q32 = lane & 31, h = lane >> 5;
  const int xm = q32 & 7;

  // XCD-chunked decode: id%8 selects XCD; each XCD owns 8 (b,h) pairs.
  const int id = blockIdx.x;
  const int jj = id >> 3;
  const int bh = (id & 7) * 8 + (jj & 7);   // 0..63 = b*NHEAD + head
  const int qt = jj >> 3;                   // 0..15
  const int q0 = qt * 128 + w * 32;

  const unsigned short* Qp = Qh + ((size_t)bh * SEQ + q0) * DK;
  const unsigned short* Kp = Kh + (size_t)bh * SEQ * DK;
  const unsigned short* Vp = Vt + (size_t)bh * DK * SEQ;

  // staging map: chunk cc (0..511) -> LDS 16B slot cc, global slot (cc&7)^(row&7)
  const int cc0 = t, cc1 = 256 + t;
  const int sr0 = cc0 >> 3, sr1 = cc1 >> 3;
  const unsigned short* kp0 = Kp + sr0 * DK  + (((cc0 & 7) ^ (sr0 & 7)) << 3);
  const unsigned short* kp1 = Kp + sr1 * DK  + (((cc1 & 7) ^ (sr1 & 7)) << 3);
  const unsigned short* vp0 = Vp + sr0 * SEQ + (((cc0 & 7) ^ (sr0 & 7)) << 3);
  const unsigned short* vp1 = Vp + sr1 * SEQ + (((cc1 & 7) ^ (sr1 & 7)) << 3);

  auto stage = [&](int buf) {  // buf is a literal at every call site
    __builtin_amdgcn_global_load_lds(
        (const __attribute__((address_space(1))) unsigned int*)kp0,
        (__attribute__((address_space(3))) unsigned int*)(&Ks[buf][cc0 * 8]), 16, 0, 0);
    __builtin_amdgcn_global_load_lds(
        (const __attribute__((address_space(1))) unsigned int*)kp1,
        (__attribute__((address_space(3))) unsigned int*)(&Ks[buf][cc1 * 8]), 16, 0, 0);
    __builtin_amdgcn_global_load_lds(
        (const __attribute__((address_space(1))) unsigned int*)vp0,
        (__attribute__((address_space(3))) unsigned int*)(&Vs[buf][cc0 * 8]), 16, 0, 0);
    __builtin_amdgcn_global_load_lds(
        (const __attribute__((address_space(1))) unsigned int*)vp1,
        (__attribute__((address_space(3))) unsigned int*)(&Vs[buf][cc1 * 8]), 16, 0, 0);
    kp0 += 64 * DK; kp1 += 64 * DK;   // next 64 keys
    vp0 += 64;      vp1 += 64;
  };

  // Q B-frags (loaded once)
  bf16x8 qf[4];
#pragma unroll
  for (int dc = 0; dc < 4; ++dc)
    qf[dc] = *(const bf16x8*)&Qp[(size_t)q32 * DK + dc * 16 + h * 8];

  f32x16 oc[2];
#pragma unroll
  for (int d0 = 0; d0 < 2; ++d0)
#pragma unroll
    for (int r = 0; r < 16; ++r) oc[d0][r] = 0.f;
  float m = -1e30f, lsum = 0.f;

  // QK of one tile from buf -> (s0out, s1out)
  auto qk = [&](int buf, f32x16& s0out, f32x16& s1out) {
    const char* Kb = (const char*)&Ks[buf][0];
    f32x16 a, b;
#pragma unroll
    for (int r = 0; r < 16; ++r) { a[r] = 0.f; b[r] = 0.f; }
    __builtin_amdgcn_s_setprio(1);
#pragma unroll
    for (int dc = 0; dc < 4; ++dc) {
      const bf16x8 kf0 = *(const bf16x8*)(Kb + (q32)*128      + (((dc * 2 + h) ^ xm) << 4));
      a = __builtin_amdgcn_mfma_f32_32x32x16_bf16(kf0, qf[dc], a, 0, 0, 0);
      const bf16x8 kf1 = *(const bf16x8*)(Kb + (32 + q32)*128 + (((dc * 2 + h) ^ xm) << 4));
      b = __builtin_amdgcn_mfma_f32_32x32x16_bf16(kf1, qf[dc], b, 0, 0, 0);
    }
    __builtin_amdgcn_s_setprio(0);
    s0out = a; s1out = b;
  };

  // softmax + PV of one tile whose scores are (st0, st1); V from Vs[vbuf]
  auto fin = [&](int vbuf, f32x16& st0, f32x16& st1) {
    const char* Vb = (const char*)&Vs[vbuf][0];
    // row max (in-lane tree + partner exchange)
    float tmx[8];
#pragma unroll
    for (int r = 0; r < 8; ++r)
      tmx[r] = fmaxf(fmaxf(st0[r], st0[r + 8]), fmaxf(st1[r], st1[r + 8]));
    const float a0 = fmaxf(fmaxf(tmx[0], tmx[1]), tmx[2]);
    const float a1 = fmaxf(fmaxf(tmx[3], tmx[4]), tmx[5]);
    const float a2 = fmaxf(tmx[6], tmx[7]);
    float pmax = fmaxf(fmaxf(a0, a1), a2);
    pmax = fmaxf(pmax, __shfl_xor(pmax, 32));

    // defer-max rescale (wave-uniform branch, THR=8 in log2 domain)
    if (!__all(pmax - m <= 8.0f)) {
      const float mnew = fmaxf(m, pmax);
      const float fsc = __builtin_amdgcn_exp2f(m - mnew);
      m = mnew;
      lsum *= fsc;
#pragma unroll
      for (int d0 = 0; d0 < 2; ++d0)
#pragma unroll
        for (int r = 0; r < 16; ++r) oc[d0][r] *= fsc;
    }

    // p = exp2(s - m); row-sum
    float rs0 = 0.f, rs1 = 0.f, rs2 = 0.f, rs3 = 0.f;
#pragma unroll
    for (int r = 0; r < 16; ++r) {
      const float p0 = __builtin_amdgcn_exp2f(st0[r] - m);
      st0[r] = p0;
      const float p1 = __builtin_amdgcn_exp2f(st1[r] - m);
      st1[r] = p1;
      if ((r & 3) == 0) rs0 += p0 + p1;
      else if ((r & 3) == 1) rs1 += p0 + p1;
      else if ((r & 3) == 2) rs2 += p0 + p1;
      else rs3 += p0 + p1;
    }
    lsum += (rs0 + rs1) + (rs2 + rs3);

    // P -> bf16 PV fragments: 16 cvt_pk + 8 permlane32_swap
    int4 pv[4];
    {
      auto s0 = __builtin_amdgcn_permlane32_swap(
          cvt_pk_bf16(st0[0], st0[1]), cvt_pk_bf16(st0[4], st0[5]), false, false);
      auto s1 = __builtin_amdgcn_permlane32_swap(
          cvt_pk_bf16(st0[2], st0[3]), cvt_pk_bf16(st0[6], st0[7]), false, false);
      pv[0] = (int4){(int)s0[0], (int)s1[0], (int)s0[1], (int)s1[1]};
      auto s2 = __builtin_amdgcn_permlane32_swap(
          cvt_pk_bf16(st0[8], st0[9]), cvt_pk_bf16(st0[12], st0[13]), false, false);
      auto s3 = __builtin_amdgcn_permlane32_swap(
          cvt_pk_bf16(st0[10], st0[11]), cvt_pk_bf16(st0[14], st0[15]), false, false);
      pv[1] = (int4){(int)s2[0], (int)s3[0], (int)s2[1], (int)s3[1]};
      auto s4 = __builtin_amdgcn_permlane32_swap(
          cvt_pk_bf16(st1[0], st1[1]), cvt_pk_bf16(st1[4], st1[5]), false, false);
      auto s5 = __builtin_amdgcn_permlane32_swap(
          cvt_pk_bf16(st1[2], st1[3]), cvt_pk_bf16(st1[6], st1[7]), false, false);
      pv[2] = (int4){(int)s4[0], (int)s5[0], (int)s4[1], (int)s5[1]};
      auto s6 = __builtin_amdgcn_permlane32_swap(
          cvt_pk_bf16(st1[8], st1[9]), cvt_pk_bf16(st1[12], st1[13]), false, false);
      auto s7 = __builtin_amdgcn_permlane32_swap(
          cvt_pk_bf16(st1[10], st1[11]), cvt_pk_bf16(st1[14], st1[15]), false, false);
      pv[3] = (int4){(int)s6[0], (int)s7[0], (int)s6[1], (int)s7[1]};
    }

    __builtin_amdgcn_s_setprio(1);
#pragma unroll
    for (int ks = 0; ks < 4; ++ks) {
      union { int4 i; bf16x8 v; } pu;
      pu.i = pv[ks];
#pragma unroll
      for (int d0 = 0; d0 < 2; ++d0) {
        const bf16x8 vf = *(const bf16x8*)(Vb + (d0 * 32 + q32) * 128 + (((ks * 2 + h) ^ xm) << 4));
        oc[d0] = __builtin_amdgcn_mfma_f32_32x32x16_bf16(vf, pu.v, oc[d0], 0, 0, 0);
      }
    }
    __builtin_amdgcn_s_setprio(0);
  };

  f32x16 stA0, stA1, stB0, stB1;

  // prologue: stage tiles 0,1; QK(0) -> A
  stage(0);
  stage(1);
  __syncthreads();
  qk(0, stA0, stA1);

  // main: t = 0..29, unroll 6 (static buffer parity: bufs %3, scores A/B %2)
#pragma unroll 1
  for (int it = 0; it < 5; ++it) {
    stage(2); qk(1, stB0, stB1); fin(0, stA0, stA1); __syncthreads();
    stage(0); qk(2, stA0, stA1); fin(1, stB0, stB1); __syncthreads();
    stage(1); qk(0, stB0, stB1); fin(2, stA0, stA1); __syncthreads();
    stage(2); qk(1, stA0, stA1); fin(0, stB0, stB1); __syncthreads();
    stage(0); qk(2, stB0, stB1); fin(1, stA0, stA1); __syncthreads();
    stage(1); qk(0, stA0, stA1); fin(2, stB0, stB1); __syncthreads();
  }
  // tail: t=30 (QK(31) from buf1, fin(30) from buf0), then fin(31)
  qk(1, stB0, stB1);
  fin(0, stA0, stA1);
  __syncthreads();
  fin(1, stB0, stB1);

  // epilogue: combine partner sums, normalize, pack 4 bf16 (8B) stores
  lsum += __shfl_xor(lsum, 32);
  const float inv = 1.f / lsum;
  unsigned short* Cp = Ctx + ((size_t)(bh >> 4) * SEQ + q0 + q32) * D_MODEL + (bh & 15) * DK;
#pragma unroll
  for (int d0 = 0; d0 < 2; ++d0)
#pragma unroll
    for (int rq = 0; rq < 4; ++rq) {
      const int dbase = d0 * 32 + 8 * rq + 4 * h;
      uint2 w2;
      w2.x = cvt_pk_bf16(oc[d0][4 * rq + 0] * inv, oc[d0][4 * rq + 1] * inv);
      w2.y = cvt_pk_bf16(oc[d0][4 * rq + 2] * inv, oc[d0][4 * rq + 3] * inv);
      *(uint2*)(Cp + dbase) = w2;
    }
}

extern "C" void kernel_launch(void* const* d_in, const int* in_sizes, int n_in,
                              void* d_out, int out_size, void* d_ws, size_t ws_size,
                              hipStream_t stream) {
  const float* query = (const float*)d_in[0];
  const float* key   = (const float*)d_in[1];
  const float* value = (const float*)d_in[2];
  const float* wq = (const float*)d_in[3];
  const float* bq = (const float*)d_in[4];
  const float* wk = (const float*)d_in[5];
  const float* bk = (const float*)d_in[6];
  const float* wv = (const float*)d_in[7];
  const float* bv = (const float*)d_in[8];
  const float* wo = (const float*)d_in[9];
  const float* bo = (const float*)d_in[10];

  unsigned short* ws = (unsigned short*)d_ws;
  const size_t TA = (size_t)MROWS * D_MODEL;
  const size_t TW = (size_t)D_MODEL * D_MODEL;
  unsigned short* qb  = ws;
  unsigned short* kb  = qb + TA;
  unsigned short* vb  = kb + TA;
  unsigned short* wqb = vb + TA;
  unsigned short* wkb = wqb + TW;
  unsigned short* wvb = wkb + TW;
  unsigned short* wob = wvb + TW;
  unsigned short* Qh  = wob + TW;   // [B,H,S,64], pre-scaled
  unsigned short* Kh  = Qh + TA;    // [B,H,S,64]
  unsigned short* Vt  = Kh + TA;    // [B,H,64,S]
  unsigned short* Cb  = Vt + TA;    // ctx bf16 [B*S][1024]

  cvt_all<<<dim3(14336), 256, 0, stream>>>(query, key, value, wq, wk, wv, wo,
                                           qb, kb, vb, wqb, wkb, wvb, wob);
  gemm_qkv<<<dim3(1536), 256, 0, stream>>>(qb, kb, vb, wqb, wkb, wvb,
                                           bq, bk, bv, Qh, Kh, Vt);
  attn_mfma<<<dim3(1024), 256, 0, stream>>>(Qh, Kh, Vt, Cb);
  gemm_out<<<dim3(512), 256, 0, stream>>>(Cb, wob, bo, (float*)d_out);
}